// Round 5
// baseline (271.054 us; speedup 1.0000x reference)
//
#include <hip/hip_runtime.h>

// ---------------------------------------------------------------------------
// context = softmax((q@Wq+bq)(k@Wk+bk)^T / 32) @ (v@Wv+bv)
// S=4096, H=D=1024. fp32 in/out, bf16 MFMA internally.
// GEMM core: 128x128 tile, BK=64 (32 KB LDS), global_load_lds width-16,
// XOR-8 chunk swizzle, band-swizzled grid, v_mfma_f32_32x32x16_bf16.
//
// ws layout (MB):
//   [ 0, 6)  Wt  bf16 [3][1024][1024]
//   [ 6,30)  xb  bf16 [3][4096][1024]   (q,k,v cast)
//   [30,46)  pr  bf16 [2][4096][1024]   (Q,K projections)
//   [46,54)  Vt  bf16 [1024][4096]      (written by V-projection epilogue)
//   [54,86)  S   bf16 [4096][4096]      (scores -> softmaxed in place)
//   [ 0,32)  p0,p1 fp32 PV partials     (dead Wt/xb/pr region at PV time;
//                                        MUST stay below 46 MB = live Vt!)
// ---------------------------------------------------------------------------

typedef short short4v __attribute__((ext_vector_type(4)));
typedef short short8  __attribute__((ext_vector_type(8)));
typedef float f32x16  __attribute__((ext_vector_type(16)));

#define MFMA32 __builtin_amdgcn_mfma_f32_32x32x16_bf16

__device__ __forceinline__ short f2bf(float f) {
    union { float f; unsigned u; } x; x.f = f;
    unsigned r = (x.u + 0x7FFFu + ((x.u >> 16) & 1u)) >> 16;  // RNE
    return (short)r;
}
__device__ __forceinline__ float bf2f(short s) {
    union { unsigned u; float f; } x;
    x.u = ((unsigned)(unsigned short)s) << 16; return x.f;
}
__device__ __forceinline__ void store_out(short* p, float v) { *p = f2bf(v); }
__device__ __forceinline__ void store_out(float* p, float v) { *p = v; }

// async global->LDS, 16B/lane. LDS dest = wave-uniform base + lane*16.
__device__ __forceinline__ void gl2lds(const short* g, short* l) {
    __builtin_amdgcn_global_load_lds(
        (const __attribute__((address_space(1))) void*)g,
        (__attribute__((address_space(3))) void*)l, 16, 0, 0);
}

// --- W[k][n] fp32 -> Wt[z][n][k] bf16 ------------------------------------
__global__ __launch_bounds__(256) void prep_w(
    const float* __restrict__ W0, const float* __restrict__ W1,
    const float* __restrict__ W2, short* __restrict__ Wt)
{
    __shared__ float tile[64][65];
    const float* W = blockIdx.z == 0 ? W0 : (blockIdx.z == 1 ? W1 : W2);
    short* T = Wt + (size_t)blockIdx.z * 1048576;
    const int c0 = blockIdx.x * 64;
    const int r0 = blockIdx.y * 64;
    const int tx = threadIdx.x & 63;
    const int ty = threadIdx.x >> 6;
    #pragma unroll
    for (int p = 0; p < 16; ++p) {
        int r = ty + p * 4;
        tile[r][tx] = W[(size_t)(r0 + r) * 1024 + c0 + tx];
    }
    __syncthreads();
    #pragma unroll
    for (int p = 0; p < 16; ++p) {
        int r = ty + p * 4;
        T[(size_t)(c0 + r) * 1024 + r0 + tx] = f2bf(tile[tx][r]);
    }
}

// --- q,k,v fp32 -> xb bf16 -----------------------------------------------
__global__ __launch_bounds__(256) void cast_qkv(
    const float* __restrict__ q, const float* __restrict__ k,
    const float* __restrict__ v, short* __restrict__ xb)
{
    const float* src = blockIdx.z == 0 ? q : (blockIdx.z == 1 ? k : v);
    short* dst = xb + (size_t)blockIdx.z * 4194304;
    for (int i = blockIdx.x * 256 + threadIdx.x; i < 1048576; i += 256 * 1024) {
        float4 f = ((const float4*)src)[i];
        short4v o;
        o[0] = f2bf(f.x); o[1] = f2bf(f.y); o[2] = f2bf(f.z); o[3] = f2bf(f.w);
        ((short4v*)dst)[i] = o;
    }
}

// --- bf16 GEMM core: C = scale*(A @ Bt^T) [+ bias] ------------------------
// 128x128 tile, BK=64, 4 waves, each wave 64x64 as 2x2 of 32x32x16 frags.
// MODE 0: plain. MODE 1: z selects {A,Bt,C,bias}; z==2 writes Vt (transposed).
// MODE 2: split-K over z, uneven: kbeg=z*kiters*64, last z gets the remainder
//         and writes Cout; others write C + z*M*N.
template <typename TOut, int MODE, int SK = 1>
__global__ __launch_bounds__(256) void gemm_mfma(
    const short* __restrict__ A, const short* __restrict__ Bt,
    const float* __restrict__ b0, const float* __restrict__ b1,
    const float* __restrict__ b2, TOut* __restrict__ C,
    float* __restrict__ Cout, short* __restrict__ Vt,
    int M, int N, int Kd, int lda, int ldb, float scale, int kiters)
{
    constexpr int LDSN = (MODE == 1) ? (128 * 136) : (128 * 64 * 2);
    __shared__ short Lds[LDSN];
    short* As = Lds;                  // [128][64]
    short* Bs = Lds + 128 * 64;       // [128][64]

    const int t    = threadIdx.x;
    const int lane = t & 63;
    const int wv   = t >> 6;

    // band-swizzled grid: 8 m-tiles per band (XCD keeps an A-panel hot)
    const int nb  = gridDim.x;
    const int bid = blockIdx.y * nb + blockIdx.x;
    const int band   = bid / (8 * nb);
    const int within = bid - band * 8 * nb;
    const int m0 = (band * 8 + (within & 7)) * 128;
    const int n0 = (within >> 3) * 128;

    const float* bias = nullptr;
    int kbeg = 0;
    int myk  = kiters;
    float* Cw = nullptr;   // actual output pointer for MODE 2
    if constexpr (MODE == 1) {
        const int z = blockIdx.z;
        A  += (size_t)z * M * lda;
        Bt += (size_t)z * N * ldb;
        C  += (size_t)z * M * N;
        bias = z == 0 ? b0 : (z == 1 ? b1 : b2);
    }
    if constexpr (MODE == 2) {
        const int z = blockIdx.z;
        kbeg = z * kiters * 64;
        if (z == SK - 1) {
            myk = (Kd >> 6) - (SK - 1) * kiters;   // remainder
            Cw  = Cout;
        } else {
            Cw = (float*)C + (size_t)z * M * N;
        }
    }
    (void)b0; (void)b1; (void)b2; (void)Cout;

    // staging: wave w stages rows [w*32, w*32+32) of both tiles, 4 rounds.
    // round r, lane l -> row = w*32 + r*8 + (l>>3); fetches logical chunk
    // (l&7)^(l>>3), lands at physical chunk l&7  (XOR-8, key = row&7).
    const int sr = lane >> 3;
    const int sc = (lane & 7) ^ sr;
    const short* pA = A  + (size_t)(m0 + wv * 32 + sr) * lda + kbeg + sc * 8;
    const short* pB = Bt + (size_t)(n0 + wv * 32 + sr) * ldb + kbeg + sc * 8;
    const size_t a8 = (size_t)8 * lda;
    const size_t b8 = (size_t)8 * ldb;
    short* lA = As + wv * 2048;
    short* lB = Bs + wv * 2048;

    const int wm = wv & 1, wn = wv >> 1;
    const int cl = lane & 31;         // row/col within 32x32 frag
    const int g  = lane >> 5;         // k-group (0/1)
    const int xk = lane & 7;          // read-side XOR key (== row&7)

    f32x16 acc[2][2];
    #pragma unroll
    for (int i = 0; i < 2; ++i)
        #pragma unroll
        for (int j = 0; j < 2; ++j)
            acc[i][j] = (f32x16)(0.f);

    for (int kk = 0; kk < myk; ++kk) {
        #pragma unroll
        for (int r = 0; r < 4; ++r) gl2lds(pA + r * a8, lA + r * 512);
        #pragma unroll
        for (int r = 0; r < 4; ++r) gl2lds(pB + r * b8, lB + r * 512);
        pA += 64; pB += 64;
        __syncthreads();   // drains vmcnt(0): staging complete

        #pragma unroll
        for (int ks = 0; ks < 4; ++ks) {
            // A[m=cl][k=g*8+j] contiguous 8-chunk per lane-group (m74/m101)
            const int chunk = ((ks * 2 + g) ^ xk) * 8;
            short8 af[2], bfr[2];
            #pragma unroll
            for (int i = 0; i < 2; ++i)
                af[i] = *(const short8*)&As[(wm * 64 + i * 32 + cl) * 64 + chunk];
            #pragma unroll
            for (int j = 0; j < 2; ++j)
                bfr[j] = *(const short8*)&Bs[(wn * 64 + j * 32 + cl) * 64 + chunk];
            #pragma unroll
            for (int i = 0; i < 2; ++i)
                #pragma unroll
                for (int j = 0; j < 2; ++j)
                    acc[i][j] = MFMA32(af[i], bfr[j], acc[i][j], 0, 0, 0);
        }
        __syncthreads();
    }

    // ---- epilogue -----------------------------------------------------
    // 32x32 C/D layout (m74/m101): col=lane&31, row=(reg&3)+8*(reg>>2)+4*(lane>>5)
    if constexpr (MODE == 1) {
        if (blockIdx.z == 2) {
            // V-projection: transpose tile through LDS, write Vt[1024][4096]
            #pragma unroll
            for (int i = 0; i < 2; ++i) {
                #pragma unroll
                for (int j = 0; j < 2; ++j) {
                    const int colL = wn * 64 + j * 32 + cl;
                    const float bb = bias[n0 + colL];
                    #pragma unroll
                    for (int r = 0; r < 16; ++r) {
                        const int rowL = wm * 64 + i * 32 + (r & 3) + 8 * (r >> 2) + 4 * g;
                        Lds[colL * 136 + rowL] = f2bf(acc[i][j][r] * scale + bb);
                    }
                }
            }
            __syncthreads();
            const int c = t >> 1, part = t & 1;
            short* dst = Vt + (size_t)(n0 + c) * 4096 + m0 + part * 64;
            #pragma unroll
            for (int s = 0; s < 8; ++s)
                *(short8*)(dst + s * 8) =
                    *(const short8*)&Lds[c * 136 + part * 64 + s * 8];
            return;
        }
    }
    #pragma unroll
    for (int i = 0; i < 2; ++i) {
        #pragma unroll
        for (int j = 0; j < 2; ++j) {
            const int ccol = n0 + wn * 64 + j * 32 + cl;
            float bb = 0.f;
            if constexpr (MODE == 1) bb = bias[ccol];
            #pragma unroll
            for (int r = 0; r < 16; ++r) {
                const int crow = m0 + wm * 64 + i * 32 + (r & 3) + 8 * (r >> 2) + 4 * g;
                const float val = acc[i][j][r] * scale + bb;
                if constexpr (MODE == 2)
                    Cw[(size_t)crow * N + ccol] = val;
                else
                    store_out(&C[(size_t)crow * N + ccol], val);
            }
        }
    }
}

// --- row softmax in place over bf16 S[4096][4096] -------------------------
__global__ __launch_bounds__(256) void softmax_bf16(short* __restrict__ S)
{
    const int row = blockIdx.x;
    short8* r8 = (short8*)(S + (size_t)row * 4096);
    const int t = threadIdx.x;

    float x[16];
    #pragma unroll
    for (int i = 0; i < 2; ++i) {
        short8 raw = r8[t + 256 * i];
        #pragma unroll
        for (int j = 0; j < 8; ++j) x[8 * i + j] = bf2f(raw[j]);
    }
    float m = -1e30f;
    #pragma unroll
    for (int i = 0; i < 16; ++i) m = fmaxf(m, x[i]);
    #pragma unroll
    for (int off = 32; off > 0; off >>= 1) m = fmaxf(m, __shfl_xor(m, off));

    __shared__ float redm[4], reds[4];
    const int wv = t >> 6;
    if ((t & 63) == 0) redm[wv] = m;
    __syncthreads();
    m = fmaxf(fmaxf(redm[0], redm[1]), fmaxf(redm[2], redm[3]));

    float s = 0.f;
    #pragma unroll
    for (int i = 0; i < 16; ++i) { x[i] = __expf(x[i] - m); s += x[i]; }
    #pragma unroll
    for (int off = 32; off > 0; off >>= 1) s += __shfl_xor(s, off);
    if ((t & 63) == 0) reds[wv] = s;
    __syncthreads();
    s = reds[0] + reds[1] + reds[2] + reds[3];
    const float inv = 1.f / s;

    #pragma unroll
    for (int i = 0; i < 2; ++i) {
        short8 o;
        #pragma unroll
        for (int j = 0; j < 8; ++j) o[j] = f2bf(x[8 * i + j] * inv);
        r8[t + 256 * i] = o;
    }
}

// --- out += p0 + p1 (split-K combine; out already holds last-z part) ------
__global__ __launch_bounds__(256) void combine3(
    const float* __restrict__ p0, const float* __restrict__ p1,
    float* __restrict__ out)
{
    for (int i = blockIdx.x * 256 + threadIdx.x; i < 1048576; i += 256 * 1024) {
        float4 a = ((const float4*)p0)[i];
        float4 b = ((const float4*)p1)[i];
        float4 o = ((const float4*)out)[i];
        o.x += a.x + b.x; o.y += a.y + b.y;
        o.z += a.z + b.z; o.w += a.w + b.w;
        ((float4*)out)[i] = o;
    }
}

extern "C" void kernel_launch(void* const* d_in, const int* in_sizes, int n_in,
                              void* d_out, int out_size, void* d_ws, size_t ws_size,
                              hipStream_t stream)
{
    const float* q  = (const float*)d_in[0];
    const float* k  = (const float*)d_in[1];
    const float* v  = (const float*)d_in[2];
    const float* Wq = (const float*)d_in[3];
    const float* bq = (const float*)d_in[4];
    const float* Wk = (const float*)d_in[5];
    const float* bk = (const float*)d_in[6];
    const float* Wv = (const float*)d_in[7];
    const float* bv = (const float*)d_in[8];
    float* out = (float*)d_out;

    char* ws = (char*)d_ws;
    const size_t MB = 1ull << 20;
    short* Wt = (short*)(ws + 0);         // 3 x 1M shorts
    short* xb = (short*)(ws + 6 * MB);    // 3 x 4M shorts
    short* pr = (short*)(ws + 30 * MB);   // 2 x 4M shorts (Q,K)
    short* Vt = (short*)(ws + 46 * MB);   // 4M shorts
    short* S  = (short*)(ws + 54 * MB);   // 16M shorts
    float* pp = (float*)(ws + 0);         // 2 x 4M floats, [0,32) MB only!

    // 1) W^T + cast, q/k/v cast
    prep_w<<<dim3(16, 16, 3), 256, 0, stream>>>(Wq, Wk, Wv, Wt);
    cast_qkv<<<dim3(1024, 1, 3), 256, 0, stream>>>(q, k, v, xb);
    // 2) projections: Q,K -> pr; V -> Vt (transposed in epilogue)
    gemm_mfma<short, 1><<<dim3(8, 32, 3), 256, 0, stream>>>(
        xb, Wt, bq, bk, bv, pr, nullptr, Vt,
        4096, 1024, 1024, 1024, 1024, 1.f, 16);
    // 3) S = Q K^T / 32
    gemm_mfma<short, 0><<<dim3(32, 32), 256, 0, stream>>>(
        pr, pr + 4194304, nullptr, nullptr, nullptr, S, nullptr, nullptr,
        4096, 4096, 1024, 1024, 1024, 0.03125f, 16);
    // 4) softmax rows in place (bf16)
    softmax_bf16<<<4096, 256, 0, stream>>>(S);
    // 5) P @ V  (split-K=3, uneven 21/21/22: z<2 -> partials, z==2 -> out)
    gemm_mfma<float, 2, 3><<<dim3(8, 32, 3), 256, 0, stream>>>(
        S, Vt, nullptr, nullptr, nullptr, pp, out, nullptr,
        4096, 1024, 4096, 4096, 4096, 1.f, 21);
    // 6) out += p0 + p1
    combine3<<<1024, 256, 0, stream>>>(pp, pp + 4194304, out);
}

// Round 6
// 270.511 us; speedup vs baseline: 1.0020x; 1.0020x over previous
//
#include <hip/hip_runtime.h>

// ---------------------------------------------------------------------------
// context = softmax((q@Wq+bq)(k@Wk+bk)^T / 32) @ (v@Wv+bv)
// S=4096, H=D=1024. fp32 in/out, bf16 MFMA internally.
// GEMM core: 128x128 tile, BK=64 (32 KB LDS), global_load_lds width-16,
// XOR-8 chunk swizzle, band-swizzled grid, v_mfma_f32_16x16x32_bf16
// (16 independent accumulator chains — 32x32 variant regressed, round 5).
//
// ws layout (MB):
//   [ 0, 6)  Wt  bf16 [3][1024][1024]
//   [ 6,30)  xb  bf16 [3][4096][1024]   (q,k,v cast)
//   [30,46)  pr  bf16 [2][4096][1024]   (Q,K projections)
//   [46,54)  Vt  bf16 [1024][4096]      (written by V-projection epilogue)
//   [54,86)  S   bf16 [4096][4096]      (scores -> softmaxed in place)
//   [ 0,32)  p0,p1 fp32 PV partials     (dead Wt/xb/pr region at PV time;
//                                        MUST stay below 46 MB = live Vt!)
// ---------------------------------------------------------------------------

typedef short short4v __attribute__((ext_vector_type(4)));
typedef short short8  __attribute__((ext_vector_type(8)));
typedef float f32x4   __attribute__((ext_vector_type(4)));

#define MFMA16 __builtin_amdgcn_mfma_f32_16x16x32_bf16

__device__ __forceinline__ short f2bf(float f) {
    union { float f; unsigned u; } x; x.f = f;
    unsigned r = (x.u + 0x7FFFu + ((x.u >> 16) & 1u)) >> 16;  // RNE
    return (short)r;
}
__device__ __forceinline__ float bf2f(short s) {
    union { unsigned u; float f; } x;
    x.u = ((unsigned)(unsigned short)s) << 16; return x.f;
}
__device__ __forceinline__ void store_out(short* p, float v) { *p = f2bf(v); }
__device__ __forceinline__ void store_out(float* p, float v) { *p = v; }

// async global->LDS, 16B/lane. LDS dest = wave-uniform base + lane*16.
__device__ __forceinline__ void gl2lds(const short* g, short* l) {
    __builtin_amdgcn_global_load_lds(
        (const __attribute__((address_space(1))) void*)g,
        (__attribute__((address_space(3))) void*)l, 16, 0, 0);
}

// --- merged prep: z<3: W[k][n] fp32 -> Wt[z][n][k] bf16 (transpose+cast);
//                  z>=3: q/k/v fp32 -> xb[z-3] bf16 (straight cast) ----------
__global__ __launch_bounds__(256) void prep_all(
    const float* __restrict__ W0, const float* __restrict__ W1,
    const float* __restrict__ W2, short* __restrict__ Wt,
    const float* __restrict__ q, const float* __restrict__ k,
    const float* __restrict__ v, short* __restrict__ xb)
{
    const int z = blockIdx.z;
    if (z < 3) {
        __shared__ float tile[64][65];
        const float* W = z == 0 ? W0 : (z == 1 ? W1 : W2);
        short* T = Wt + (size_t)z * 1048576;
        const int c0 = blockIdx.x * 64;
        const int r0 = blockIdx.y * 64;
        const int tx = threadIdx.x & 63;
        const int ty = threadIdx.x >> 6;
        #pragma unroll
        for (int p = 0; p < 16; ++p) {
            int r = ty + p * 4;
            tile[r][tx] = W[(size_t)(r0 + r) * 1024 + c0 + tx];
        }
        __syncthreads();
        #pragma unroll
        for (int p = 0; p < 16; ++p) {
            int r = ty + p * 4;
            T[(size_t)(c0 + r) * 1024 + r0 + tx] = f2bf(tile[tx][r]);
        }
    } else {
        const float* src = z == 3 ? q : (z == 4 ? k : v);
        short* dst = xb + (size_t)(z - 3) * 4194304;
        const int blk = blockIdx.y * 16 + blockIdx.x;   // 0..255
        for (int i = blk * 256 + threadIdx.x; i < 1048576; i += 256 * 256) {
            float4 f = ((const float4*)src)[i];
            short4v o;
            o[0] = f2bf(f.x); o[1] = f2bf(f.y);
            o[2] = f2bf(f.z); o[3] = f2bf(f.w);
            ((short4v*)dst)[i] = o;
        }
    }
}

// --- bf16 GEMM core: C = scale*(A @ Bt^T) [+ bias] ------------------------
// 128x128 tile, BK=64, 4 waves, 4x4 16x16x32 frags per wave, 2 K-halves.
// MODE 0: plain. MODE 1: z selects {A,Bt,C,bias}; z==2 writes Vt (transposed).
// MODE 2: split-K over z, uneven: kbeg=z*kiters*64; last z takes the
//         remainder and writes Cout, others write C + z*M*N.
template <typename TOut, int MODE, int SK = 1>
__global__ __launch_bounds__(256) void gemm64(
    const short* __restrict__ A, const short* __restrict__ Bt,
    const float* __restrict__ b0, const float* __restrict__ b1,
    const float* __restrict__ b2, TOut* __restrict__ C,
    float* __restrict__ Cout, short* __restrict__ Vt,
    int M, int N, int Kd, int lda, int ldb, float scale, int kiters)
{
    constexpr int LDSN = (MODE == 1) ? (128 * 136) : (128 * 64 * 2);
    __shared__ short Lds[LDSN];
    short* As = Lds;                  // [128][64]
    short* Bs = Lds + 128 * 64;       // [128][64]

    const int t    = threadIdx.x;
    const int lane = t & 63;
    const int wv   = t >> 6;

    // band-swizzled grid: 8 m-tiles per band (XCD keeps an A-panel hot)
    const int nb  = gridDim.x;
    const int bid = blockIdx.y * nb + blockIdx.x;
    const int band   = bid / (8 * nb);
    const int within = bid - band * 8 * nb;
    const int m0 = (band * 8 + (within & 7)) * 128;
    const int n0 = (within >> 3) * 128;

    const float* bias = nullptr;
    int kbeg = 0;
    int myk  = kiters;
    float* Cw = nullptr;   // actual output pointer for MODE 2
    if constexpr (MODE == 1) {
        const int z = blockIdx.z;
        A  += (size_t)z * M * lda;
        Bt += (size_t)z * N * ldb;
        C  += (size_t)z * M * N;
        bias = z == 0 ? b0 : (z == 1 ? b1 : b2);
    }
    if constexpr (MODE == 2) {
        const int z = blockIdx.z;
        kbeg = z * kiters * 64;
        if (z == SK - 1) {
            myk = (Kd >> 6) - (SK - 1) * kiters;   // remainder
            Cw  = Cout;
        } else {
            Cw = (float*)C + (size_t)z * M * N;
        }
    }
    (void)b0; (void)b1; (void)b2; (void)Cout;

    // staging: wave w stages rows [w*32, w*32+32) of both tiles, 4 rounds.
    // round r, lane l -> row = w*32 + r*8 + (l>>3); fetches logical chunk
    // (l&7)^(l>>3), lands at physical chunk l&7  (XOR-8, key = row&7).
    const int sr = lane >> 3;
    const int sc = (lane & 7) ^ sr;
    const short* pA = A  + (size_t)(m0 + wv * 32 + sr) * lda + kbeg + sc * 8;
    const short* pB = Bt + (size_t)(n0 + wv * 32 + sr) * ldb + kbeg + sc * 8;
    const size_t a8 = (size_t)8 * lda;
    const size_t b8 = (size_t)8 * ldb;
    short* lA = As + wv * 2048;
    short* lB = Bs + wv * 2048;

    const int wm = wv & 1, wn = wv >> 1;
    const int lr = lane & 15, lq = lane >> 4;
    const int xkey = lr & 7;                  // read-side XOR key (== row&7)

    f32x4 acc[4][4];
    #pragma unroll
    for (int i = 0; i < 4; ++i)
        #pragma unroll
        for (int j = 0; j < 4; ++j) {
            f32x4 z = {0.f, 0.f, 0.f, 0.f};
            acc[i][j] = z;
        }

    for (int kk = 0; kk < myk; ++kk) {
        #pragma unroll
        for (int r = 0; r < 4; ++r) gl2lds(pA + r * a8, lA + r * 512);
        #pragma unroll
        for (int r = 0; r < 4; ++r) gl2lds(pB + r * b8, lB + r * 512);
        pA += 64; pB += 64;
        __syncthreads();   // drains vmcnt(0): staging complete

        #pragma unroll
        for (int h = 0; h < 2; ++h) {
            short8 af[4], bfr[4];
            #pragma unroll
            for (int i = 0; i < 4; ++i)
                af[i] = *(const short8*)
                    &As[(wm * 64 + i * 16 + lr) * 64 + (((h * 4 + lq) ^ xkey) * 8)];
            #pragma unroll
            for (int j = 0; j < 4; ++j)
                bfr[j] = *(const short8*)
                    &Bs[(wn * 64 + j * 16 + lr) * 64 + (((h * 4 + lq) ^ xkey) * 8)];
            #pragma unroll
            for (int i = 0; i < 4; ++i)
                #pragma unroll
                for (int j = 0; j < 4; ++j)
                    acc[i][j] = MFMA16(af[i], bfr[j], acc[i][j], 0, 0, 0);
        }
        __syncthreads();
    }

    // ---- epilogue -----------------------------------------------------
    // C/D layout: col=lane&15, row=(lane>>4)*4+reg (m89/m91 verified)
    if constexpr (MODE == 1) {
        if (blockIdx.z == 2) {
            // V-projection: transpose tile through LDS, write Vt[1024][4096]
            #pragma unroll
            for (int i = 0; i < 4; ++i) {
                #pragma unroll
                for (int j = 0; j < 4; ++j) {
                    const int colL = wn * 64 + j * 16 + lr;
                    const float bb = bias[n0 + colL];
                    #pragma unroll
                    for (int r = 0; r < 4; ++r) {
                        const int rowL = wm * 64 + i * 16 + lq * 4 + r;
                        Lds[colL * 136 + rowL] = f2bf(acc[i][j][r] * scale + bb);
                    }
                }
            }
            __syncthreads();
            const int c = t >> 1, part = t & 1;
            short* dst = Vt + (size_t)(n0 + c) * 4096 + m0 + part * 64;
            #pragma unroll
            for (int s = 0; s < 8; ++s)
                *(short8*)(dst + s * 8) =
                    *(const short8*)&Lds[c * 136 + part * 64 + s * 8];
            return;
        }
    }
    #pragma unroll
    for (int i = 0; i < 4; ++i) {
        #pragma unroll
        for (int j = 0; j < 4; ++j) {
            const int crow = m0 + wm * 64 + i * 16 + lq * 4;
            const int ccol = n0 + wn * 64 + j * 16 + lr;
            float bb = 0.f;
            if constexpr (MODE == 1) bb = bias[ccol];
            #pragma unroll
            for (int r = 0; r < 4; ++r) {
                const float val = acc[i][j][r] * scale + bb;
                if constexpr (MODE == 2)
                    Cw[(size_t)(crow + r) * N + ccol] = val;
                else
                    store_out(&C[(size_t)(crow + r) * N + ccol], val);
            }
        }
    }
}

// --- row softmax in place over bf16 S[4096][4096] -------------------------
__global__ __launch_bounds__(256) void softmax_bf16(short* __restrict__ S)
{
    const int row = blockIdx.x;
    short8* r8 = (short8*)(S + (size_t)row * 4096);
    const int t = threadIdx.x;

    float x[16];
    #pragma unroll
    for (int i = 0; i < 2; ++i) {
        short8 raw = r8[t + 256 * i];
        #pragma unroll
        for (int j = 0; j < 8; ++j) x[8 * i + j] = bf2f(raw[j]);
    }
    float m = -1e30f;
    #pragma unroll
    for (int i = 0; i < 16; ++i) m = fmaxf(m, x[i]);
    #pragma unroll
    for (int off = 32; off > 0; off >>= 1) m = fmaxf(m, __shfl_xor(m, off));

    __shared__ float redm[4], reds[4];
    const int wv = t >> 6;
    if ((t & 63) == 0) redm[wv] = m;
    __syncthreads();
    m = fmaxf(fmaxf(redm[0], redm[1]), fmaxf(redm[2], redm[3]));

    float s = 0.f;
    #pragma unroll
    for (int i = 0; i < 16; ++i) { x[i] = __expf(x[i] - m); s += x[i]; }
    #pragma unroll
    for (int off = 32; off > 0; off >>= 1) s += __shfl_xor(s, off);
    if ((t & 63) == 0) reds[wv] = s;
    __syncthreads();
    s = reds[0] + reds[1] + reds[2] + reds[3];
    const float inv = 1.f / s;

    #pragma unroll
    for (int i = 0; i < 2; ++i) {
        short8 o;
        #pragma unroll
        for (int j = 0; j < 8; ++j) o[j] = f2bf(x[8 * i + j] * inv);
        r8[t + 256 * i] = o;
    }
}

// --- out += p0 + p1 (split-K combine; out already holds last-z part) ------
__global__ __launch_bounds__(256) void combine3(
    const float* __restrict__ p0, const float* __restrict__ p1,
    float* __restrict__ out)
{
    for (int i = blockIdx.x * 256 + threadIdx.x; i < 1048576; i += 256 * 1024) {
        float4 a = ((const float4*)p0)[i];
        float4 b = ((const float4*)p1)[i];
        float4 o = ((const float4*)out)[i];
        o.x += a.x + b.x; o.y += a.y + b.y;
        o.z += a.z + b.z; o.w += a.w + b.w;
        ((float4*)out)[i] = o;
    }
}

extern "C" void kernel_launch(void* const* d_in, const int* in_sizes, int n_in,
                              void* d_out, int out_size, void* d_ws, size_t ws_size,
                              hipStream_t stream)
{
    const float* q  = (const float*)d_in[0];
    const float* k  = (const float*)d_in[1];
    const float* v  = (const float*)d_in[2];
    const float* Wq = (const float*)d_in[3];
    const float* bq = (const float*)d_in[4];
    const float* Wk = (const float*)d_in[5];
    const float* bk = (const float*)d_in[6];
    const float* Wv = (const float*)d_in[7];
    const float* bv = (const float*)d_in[8];
    float* out = (float*)d_out;

    char* ws = (char*)d_ws;
    const size_t MB = 1ull << 20;
    short* Wt = (short*)(ws + 0);         // 3 x 1M shorts
    short* xb = (short*)(ws + 6 * MB);    // 3 x 4M shorts
    short* pr = (short*)(ws + 30 * MB);   // 2 x 4M shorts (Q,K)
    short* Vt = (short*)(ws + 46 * MB);   // 4M shorts
    short* S  = (short*)(ws + 54 * MB);   // 16M shorts
    float* pp = (float*)(ws + 0);         // 2 x 4M floats, [0,32) MB only!

    // 1) W^T + qkv cast (merged)
    prep_all<<<dim3(16, 16, 6), 256, 0, stream>>>(Wq, Wk, Wv, Wt, q, k, v, xb);
    // 2) projections: Q,K -> pr; V -> Vt (transposed in epilogue)
    gemm64<short, 1><<<dim3(8, 32, 3), 256, 0, stream>>>(
        xb, Wt, bq, bk, bv, pr, nullptr, Vt,
        4096, 1024, 1024, 1024, 1024, 1.f, 16);
    // 3) S = Q K^T / 32
    gemm64<short, 0><<<dim3(32, 32), 256, 0, stream>>>(
        pr, pr + 4194304, nullptr, nullptr, nullptr, S, nullptr, nullptr,
        4096, 4096, 1024, 1024, 1024, 0.03125f, 16);
    // 4) softmax rows in place (bf16)
    softmax_bf16<<<4096, 256, 0, stream>>>(S);
    // 5) P @ V  (split-K=3, uneven 21/21/22: z<2 -> partials, z==2 -> out)
    gemm64<float, 2, 3><<<dim3(8, 32, 3), 256, 0, stream>>>(
        S, Vt, nullptr, nullptr, nullptr, pp, out, nullptr,
        4096, 1024, 4096, 4096, 4096, 1.f, 21);
    // 6) out += p0 + p1
    combine3<<<1024, 256, 0, stream>>>(pp, pp + 4194304, out);
}